// Round 13
// baseline (85.515 us; speedup 1.0000x reference)
//
#include <hip/hip_runtime.h>
#include <math.h>

// SSIM (16,3,512,512) fp32, 11x11 separable Gaussian, VALID -> per-batch mean [16].
//
// Round-13: all-register design. 1 output column per thread, no LDS staging,
// no inline asm, no global_load_lds.
//  - Each lane loads its own 11-float window per tensor per row as 3 dwordx4
//    (offsets +0,+4,+7; 4B-aligned unaligned-OK). Adjacent lanes overlap ->
//    L1/L2 absorbs the ~5x amplification. Compiler inserts precise vmcnt and
//    software-pipelines loads one row ahead (registers are available).
//  - Ring = 11 x {r,d,rr+dd,rd} = 44 floats; total live ~95 regs -> pure arch
//    VGPRs (no AGPR split possible), <=128 total -> 4 waves/SIMD.
//  - Column coverage: group 0 waves at cb=0,64,128,192; group 1 at
//    cb=246,310,374,438 with c>=256 guard (windows always in-bounds, all
//    extraction indices static).
//  - 255x scaling cancels: C1 = 1e-4, C2 = 9e-4 on [0,1] data.

#define WSZ 11
#define IMG 512
#define OSZ 502
#define NT  256
#define CH_OUT 42
#define NCHUNK 12        // 12*42 = 504 >= 502

struct WinArg { float w[WSZ]; };

typedef float f4 __attribute__((ext_vector_type(4)));

#define C1V 1.0e-4f
#define C2V 9.0e-4f

__device__ __forceinline__ f4 ld4(const float* p) {
    f4 v;
    __builtin_memcpy(&v, p, 16);   // load <4 x float>, align 4 -> dwordx4
    return v;
}

// element e (0..10) of the 11-float window held in A(=+0),B(=+4),C(=+7)
#define EL(A_, B_, C_, E) ((E) < 4 ? (A_)[(E)] : ((E) < 8 ? (B_)[(E) - 4] : (C_)[(E) - 7]))

__global__ __launch_bounds__(NT, 4) void ssim_reg(
    const float* __restrict__ rawp, const float* __restrict__ dstp,
    float* __restrict__ out, WinArg wa, float inv_n)
{
    __shared__ float wred[NT / 64];

    const int tid   = threadIdx.x;
    const int lane  = tid & 63;
    const int wave  = tid >> 6;
    const int group = blockIdx.x & 1;
    const int chunk = blockIdx.x >> 1;
    const int img   = blockIdx.y;

    const int cb = wave * 64 + (group ? 246 : 0);
    const int c  = cb + lane;                     // this thread's output column
    const bool active = (group == 0) || (c >= 256);

    const int o0    = chunk * CH_OUT;
    const int olim  = min(o0 + CH_OUT, OSZ);
    const int rlast = min(o0 + CH_OUT + WSZ - 2, IMG - 1);
    const int NR    = rlast - o0 + 1;             // 52 (50 for last chunk)

    const size_t base = (size_t)img * (size_t)(IMG * IMG)
                      + (size_t)o0 * IMG + (size_t)c;
    const float* rp0 = rawp + base;
    const float* dp0 = dstp + base;

    float hs[WSZ][4];                             // ring: [slot][{r,d,rr+dd,rd}]
    float acc = 0.0f;

#pragma unroll 1
    for (int rr = 0; rr < NR; rr += WSZ) {
#pragma unroll
        for (int k = 0; k < WSZ; ++k) {
            const int klin = rr + k;
            if (klin < NR) {                      // block-uniform
                const float* rp = rp0 + (size_t)klin * IMG;
                const float* dp = dp0 + (size_t)klin * IMG;
                const f4 A = ld4(rp);     const f4 B = ld4(rp + 4);
                const f4 C = ld4(rp + 7);
                const f4 D = ld4(dp);     const f4 E = ld4(dp + 4);
                const f4 F = ld4(dp + 7);

                // ---- H-pass: 11 taps, 4 channels ----
                float s1 = 0.f, s2 = 0.f, s3 = 0.f, s4 = 0.f;
#pragma unroll
                for (int e = 0; e < WSZ; ++e) {
                    const float r  = EL(A, B, C, e);
                    const float d  = EL(D, E, F, e);
                    const float sq = fmaf(d, d, r * r);
                    const float p  = r * d;
                    const float w_ = wa.w[e];
                    s1 = fmaf(w_, r,  s1);
                    s2 = fmaf(w_, d,  s2);
                    s3 = fmaf(w_, sq, s3);
                    s4 = fmaf(w_, p,  s4);
                }
                hs[k][0] = s1; hs[k][1] = s2; hs[k][2] = s3; hs[k][3] = s4;

                // ---- V-pass + SSIM ----
                const int o = o0 + klin - (WSZ - 1);
                if (klin >= WSZ - 1 && o < olim && active) {
                    float m1 = 0.f, m2 = 0.f, m3 = 0.f, m4 = 0.f;
#pragma unroll
                    for (int i = 0; i < WSZ; ++i) {
                        const int s = (k + 1 + i) % WSZ;   // static after unroll
                        const float wi = wa.w[i];
                        m1 = fmaf(wi, hs[s][0], m1);
                        m2 = fmaf(wi, hs[s][1], m2);
                        m3 = fmaf(wi, hs[s][2], m3);
                        m4 = fmaf(wi, hs[s][3], m4);
                    }
                    const float q1 = m1 * m1, q2 = m2 * m2, mm = m1 * m2;
                    const float num = (2.f * mm + C1V) * (2.f * (m4 - mm) + C2V);
                    const float den = (q1 + q2 + C1V) * (((m3 - q1) - q2) + C2V);
                    acc += num * __builtin_amdgcn_rcpf(den);
                }
            }
        }
    }

    // ---- block reduction -> one atomicAdd per block ----
#pragma unroll
    for (int off = 32; off > 0; off >>= 1) acc += __shfl_down(acc, off, 64);
    if (lane == 0) wred[wave] = acc;
    __syncthreads();
    if (tid == 0) {
        const float tot = (wred[0] + wred[1]) + (wred[2] + wred[3]);
        atomicAdd(out + img / 3, tot * inv_n);
    }
}

extern "C" void kernel_launch(void* const* d_in, const int* in_sizes, int n_in,
                              void* d_out, int out_size, void* d_ws, size_t ws_size,
                              hipStream_t stream) {
    const float* raw = (const float*)d_in[0];
    const float* dst = (const float*)d_in[1];
    float* out = (float*)d_out;

    hipMemsetAsync(out, 0, (size_t)out_size * sizeof(float), stream);

    WinArg wa;
    double g[WSZ], s = 0.0;
    for (int i = 0; i < WSZ; ++i) {
        double ax = (double)i - (double)(WSZ - 1) / 2.0;
        g[i] = exp(-(ax * ax) / (2.0 * 1.5 * 1.5));
        s += g[i];
    }
    for (int i = 0; i < WSZ; ++i) wa.w[i] = (float)(g[i] / s);

    const float inv_n = (float)(1.0 / (3.0 * (double)OSZ * (double)OSZ));

    dim3 grid(2 * NCHUNK, 48);
    ssim_reg<<<grid, NT, 0, stream>>>(raw, dst, out, wa, inv_n);
}